// Round 18
// baseline (105.586 us; speedup 1.0000x reference)
//
#include <hip/hip_runtime.h>
#include <hip/hip_bf16.h>

// Problem constants (B=4, S=4096, A=2, H=8, DH=128, DM=2048)
#define T_TOK 16384
#define NH 8
#define DHD 128
#define DMD 2048
#define KTOT 256       // A=2 slots * DH=128
#define BCAP 384       // per-bucket row capacity (mean 256 + 8 sigma)
#define CSTR 64        // cursor stride in ints (256B) — one L2 channel per key

typedef __attribute__((ext_vector_type(8))) short bf16x8;
typedef __attribute__((ext_vector_type(4))) float f32x4;

__device__ inline short f2b(float x) {
    __hip_bfloat16 h = __float2bfloat16(x);
    return *reinterpret_cast<short*>(&h);
}

// async global -> LDS, 16B per lane (dest = wave-uniform base + lane*16)
__device__ inline void gll16(const void* g, void* l) {
    __builtin_amdgcn_global_load_lds(
        (const __attribute__((address_space(1))) void*)g,
        (__attribute__((address_space(3))) void*)l, 16, 0, 0);
}

// ---------------- ws layout (bytes) ----------------
// 0      : cursor[64*64] int (16 KB; key k at cursor[k*64] — 256B stride so
//          the 64 atomic counters hit 64 distinct L2 channels)
// 16384  : perm[64*384] int (98.3 KB)
// 262144 : Wt  bf16 [8][2048][128]     (4 MB)
// 4456448: Apk bf16 [64][384][256]     (12.6 MB; slack rows stay poisoned —
//          finite bf16, masked at epilogue by s_tok<0)

__global__ __launch_bounds__(1024) void k_init(int* __restrict__ cursor) {
    cursor[blockIdx.x * 1024 + threadIdx.x] = 0;   // 4096 ints = 16 KB
}

// fused work: blocks [0,512) = scatter+pack into capacity buckets (8 threads
// per token); blocks [512,768) = W -> Wt bf16 transpose.
__global__ __launch_bounds__(256) void k_work(
    const int* __restrict__ idx, const float* __restrict__ emb,
    const float* __restrict__ probs, const float* __restrict__ W,
    int* __restrict__ cursor, int* __restrict__ perm,
    short* __restrict__ Apk, short* __restrict__ Wt) {
    if (blockIdx.x < 512) {
        int g = blockIdx.x * 256 + threadIdx.x;   // 131072 threads = 16384 x 8
        int t = g >> 3, sub = g & 7;
        int lane = threadIdx.x & 63;
        int pos = 0;
        if (sub == 0) {
            int key = idx[2 * t] * NH + idx[2 * t + 1];
            int slot = atomicAdd(&cursor[key * CSTR], 1);
            pos = (slot < BCAP) ? (key * BCAP + slot) : -1;  // clamp: fail loud
            if (pos >= 0) perm[pos] = t;
        }
        pos = __shfl(pos, lane & ~7, 64);          // broadcast from group leader
        if (pos < 0) return;
        int a = sub >> 2;                          // slot 0 or 1
        float p = probs[2 * t + a];
        const f32x4* s =
            (const f32x4*)(emb + ((size_t)(2 * t + a)) * DHD + (sub & 3) * 32);
        short* dst = Apk + (size_t)pos * KTOT + sub * 32;
#pragma unroll
        for (int c = 0; c < 4; ++c) {
            f32x4 f0 = s[2 * c], f1 = s[2 * c + 1];
            bf16x8 o;
            o[0] = f2b(p * f0.x); o[1] = f2b(p * f0.y);
            o[2] = f2b(p * f0.z); o[3] = f2b(p * f0.w);
            o[4] = f2b(p * f1.x); o[5] = f2b(p * f1.y);
            o[6] = f2b(p * f1.z); o[7] = f2b(p * f1.w);
            *(bf16x8*)(dst + c * 8) = o;
        }
    } else {
        __shared__ float Ws[DHD][65];
        int bx = blockIdx.x - 512;
        int h = bx >> 5, m0 = (bx & 31) * 64;
        int tid = threadIdx.x;
        for (int i = tid; i < DHD * 64; i += 256) {
            int d = i >> 6, m = i & 63;
            Ws[d][m] = W[((size_t)h * DHD + d) * DMD + m0 + m];
        }
        __syncthreads();
        for (int i = tid; i < 64 * 16; i += 256) {
            int m = i >> 4, d0 = (i & 15) * 8;
            bf16x8 o;
#pragma unroll
            for (int j = 0; j < 8; ++j) o[j] = f2b(Ws[d0 + j][m]);
            *(bf16x8*)(Wt + ((size_t)h * DMD + m0 + m) * DHD + d0) = o;
        }
    }
}

// GEMM v5: K-loop = proven R15 core (BM=128, BN=256, BK=64, 512 thr, gll16 +
// rule-21 XOR swizzle, 2 barriers/K-step, 48KB LDS -> 3 blocks/CU).
// NEW: coalesced-store epilogue — acc round-trips through LDS (T[32][260],
// 4 chunks of 32 rows) so each out row is ONE global_store_dwordx4 burst of
// 1KB contiguous, replacing 4x64B scattered segments per wave-instruction.
// Theory: gemm is store-pattern-bound (achieved write BW ~2.7 TB/s vs 6.5
// attainable).
__global__ __launch_bounds__(512) void k_gemm(
    const short* __restrict__ Apk, const float* __restrict__ probs,
    const short* __restrict__ Wt, const float* __restrict__ bias,
    const int* __restrict__ perm, const int* __restrict__ cursor,
    float* __restrict__ out) {
    int lin  = blockIdx.x;
    int work = (lin & 7) * 192 + (lin >> 3);
    int tile_id = work >> 3;
    int ncol    = (work & 7) * 256;
    int key = tile_id / 3, s = tile_id - key * 3;
    int nrows = cursor[key * CSTR] - s * 128;
    if (nrows <= 0) return;
    if (nrows > 128) nrows = 128;
    int row0 = key * BCAP + s * 128;
    int h0 = key >> 3, h1 = key & 7;

    __shared__ union SM {
        struct { short As[128 * 64]; short Bs[256 * 64]; } k;  // 48 KB
        float T[32][260];                                      // 33.3 KB
    } sm;
    __shared__ int   s_tok[128];
    __shared__ float s_p0[128], s_p1[128];

    int tid = threadIdx.x;
    int lane = tid & 63, wave = tid >> 6;

    if (tid < 128) {
        int t = -1; float p0 = 0.f, p1 = 0.f;
        if (tid < nrows) {
            t = perm[row0 + tid];
            p0 = probs[2 * t];
            p1 = probs[2 * t + 1];
        }
        s_tok[tid] = t; s_p0[tid] = p0; s_p1[tid] = p1;
    }

    f32x4 acc[4][4];
#pragma unroll
    for (int i = 0; i < 4; ++i)
#pragma unroll
        for (int j = 0; j < 4; ++j) acc[i][j] = (f32x4){0.f, 0.f, 0.f, 0.f};

    int wm = (wave >> 2) * 64;
    int wn = (wave & 3) * 64;
    int l15 = lane & 15, lq = lane >> 4;

    int srcr = tid >> 3;
    int cs   = (tid & 7) ^ (srcr & 7);

    for (int ks = 0; ks < 4; ++ks) {
        int h     = (ks < 2) ? h0 : h1;
        int kg0   = ks * 64;
        int dbase = (ks & 1) * 64;
#pragma unroll
        for (int rd = 0; rd < 2; ++rd) {
            int r = rd * 64 + srcr;
            short* ldst = sm.k.As + (rd * 512 + wave * 64) * 8;
            gll16(Apk + (size_t)(row0 + r) * KTOT + kg0 + cs * 8, ldst);
        }
#pragma unroll
        for (int rd = 0; rd < 4; ++rd) {
            int r = rd * 64 + srcr;
            short* ldst = sm.k.Bs + (rd * 512 + wave * 64) * 8;
            gll16(Wt + ((size_t)h * DMD + ncol + r) * DHD + dbase + cs * 8, ldst);
        }
        __syncthreads();

#pragma unroll
        for (int ki = 0; ki < 2; ++ki) {
            bf16x8 af[4], bfr[4];
#pragma unroll
            for (int mi = 0; mi < 4; ++mi) {
                int R  = wm + mi * 16 + l15;
                int ch = (ki * 4 + lq) ^ (R & 7);
                af[mi] = *(const bf16x8*)&sm.k.As[R * 64 + ch * 8];
            }
#pragma unroll
            for (int ni = 0; ni < 4; ++ni) {
                int N  = wn + ni * 16 + l15;
                int ch = (ki * 4 + lq) ^ (N & 7);
                bfr[ni] = *(const bf16x8*)&sm.k.Bs[N * 64 + ch * 8];
            }
#pragma unroll
            for (int mi = 0; mi < 4; ++mi)
#pragma unroll
                for (int ni = 0; ni < 4; ++ni)
                    acc[mi][ni] = __builtin_amdgcn_mfma_f32_16x16x32_bf16(
                        af[mi], bfr[ni], acc[mi][ni], 0, 0, 0);
        }
        __syncthreads();
    }

    // ---- coalesced-store epilogue: 4 chunks of 32 rows via LDS transpose
    // bias vectors hoisted: col = ncol + lane*4 .. +3 (16B-aligned)
    f32x4 b0v = *(const f32x4*)&bias[h0 * DMD + ncol + lane * 4];
    f32x4 b1v = *(const f32x4*)&bias[h1 * DMD + ncol + lane * 4];

#pragma unroll
    for (int cb = 0; cb < 4; ++cb) {
        int c0 = cb * 32;
        __syncthreads();   // T free (K-loop done / prev chunk's reads done)
        if (wm == (c0 & 64)) {
            int mibase = (c0 & 32) ? 2 : 0;
#pragma unroll
            for (int mm = 0; mm < 2; ++mm) {
#pragma unroll
                for (int ni = 0; ni < 4; ++ni)
#pragma unroll
                    for (int r = 0; r < 4; ++r)
                        sm.T[mm * 16 + lq * 4 + r][wn + ni * 16 + l15] =
                            acc[mibase + mm][ni][r];
            }
        }
        __syncthreads();   // T filled
        // readback: wave handles 4 rows; one dwordx4 burst per row (1KB)
#pragma unroll
        for (int rr = 0; rr < 4; ++rr) {
            int lrow = wave * 4 + rr;        // 0..31
            int i = c0 + lrow;               // global row in tile
            int t = s_tok[i];
            if (t >= 0) {
                f32x4 v = *(const f32x4*)&sm.T[lrow][lane * 4];
                float p0 = s_p0[i], p1 = s_p1[i];
                v.x += p0 * b0v.x + p1 * b1v.x;
                v.y += p0 * b0v.y + p1 * b1v.y;
                v.z += p0 * b0v.z + p1 * b1v.z;
                v.w += p0 * b0v.w + p1 * b1v.w;
                __builtin_nontemporal_store(
                    v, (f32x4*)&out[(size_t)t * DMD + ncol + lane * 4]);
            }
        }
    }
}

extern "C" void kernel_launch(void* const* d_in, const int* in_sizes, int n_in,
                              void* d_out, int out_size, void* d_ws, size_t ws_size,
                              hipStream_t stream) {
    const float* emb      = (const float*)d_in[0];  // (B,S,A,DH) f32
    const int*   sel_idx  = (const int*)d_in[1];    // (B,S,A) i32
    const float* sel_prob = (const float*)d_in[2];  // (B,S,A) f32
    const float* W        = (const float*)d_in[3];  // (H,DH,DM) f32
    const float* bias     = (const float*)d_in[4];  // (H,DM) f32
    float* out = (float*)d_out;

    char* ws = (char*)d_ws;
    int* cursor = (int*)(ws + 0);
    int* perm   = (int*)(ws + 16384);
    short* Wt   = (short*)(ws + 262144);
    short* Apk  = (short*)(ws + 4456448);

    k_init<<<dim3(4), dim3(1024), 0, stream>>>(cursor);
    k_work<<<dim3(768), dim3(256), 0, stream>>>(
        sel_idx, emb, sel_prob, W, cursor, perm, Apk, Wt);
    k_gemm<<<dim3(1536), dim3(512), 0, stream>>>(
        Apk, sel_prob, Wt, bias, perm, cursor, out);
}

// Round 19
// 74.570 us; speedup vs baseline: 1.4159x; 1.4159x over previous
//
#include <hip/hip_runtime.h>
#include <hip/hip_bf16.h>

// Problem constants (B=4, S=4096, A=2, H=8, DH=128, DM=2048)
#define T_TOK 16384
#define NH 8
#define DHD 128
#define DMD 2048
#define KTOT 256       // A=2 slots * DH=128
#define BCAP 384       // per-bucket row capacity (mean 256 + 8 sigma)
#define CSTR 64        // cursor stride in ints (256B) — one L2 channel per key

typedef __attribute__((ext_vector_type(8))) short bf16x8;
typedef __attribute__((ext_vector_type(4))) float f32x4;

__device__ inline short f2b(float x) {
    __hip_bfloat16 h = __float2bfloat16(x);
    return *reinterpret_cast<short*>(&h);
}

// async global -> LDS, 16B per lane (dest = wave-uniform base + lane*16)
__device__ inline void gll16(const void* g, void* l) {
    __builtin_amdgcn_global_load_lds(
        (const __attribute__((address_space(1))) void*)g,
        (__attribute__((address_space(3))) void*)l, 16, 0, 0);
}

// ---------------- ws layout (bytes) ----------------
// 0      : cursor[64*64] int (16 KB; key k at cursor[k*64] — 256B stride so
//          the 64 atomic counters hit 64 distinct L2 channels)
// 16384  : perm[64*384] int (98.3 KB)
// 262144 : Wt  bf16 [8][2048][128]     (4 MB)
// 4456448: Apk bf16 [64][384][256]     (12.6 MB; slack rows stay poisoned —
//          finite bf16, masked at epilogue by s_tok<0)

__global__ __launch_bounds__(1024) void k_init(int* __restrict__ cursor) {
    cursor[blockIdx.x * 1024 + threadIdx.x] = 0;   // 4096 ints = 16 KB
}

// fused work: blocks [0,512) = scatter+pack into capacity buckets (8 threads
// per token); blocks [512,768) = W -> Wt bf16 transpose.
__global__ __launch_bounds__(256) void k_work(
    const int* __restrict__ idx, const float* __restrict__ emb,
    const float* __restrict__ probs, const float* __restrict__ W,
    int* __restrict__ cursor, int* __restrict__ perm,
    short* __restrict__ Apk, short* __restrict__ Wt) {
    if (blockIdx.x < 512) {
        int g = blockIdx.x * 256 + threadIdx.x;   // 131072 threads = 16384 x 8
        int t = g >> 3, sub = g & 7;
        int lane = threadIdx.x & 63;
        int pos = 0;
        if (sub == 0) {
            int key = idx[2 * t] * NH + idx[2 * t + 1];
            int slot = atomicAdd(&cursor[key * CSTR], 1);
            pos = (slot < BCAP) ? (key * BCAP + slot) : -1;  // clamp: fail loud
            if (pos >= 0) perm[pos] = t;
        }
        pos = __shfl(pos, lane & ~7, 64);          // broadcast from group leader
        if (pos < 0) return;
        int a = sub >> 2;                          // slot 0 or 1
        float p = probs[2 * t + a];
        const f32x4* s =
            (const f32x4*)(emb + ((size_t)(2 * t + a)) * DHD + (sub & 3) * 32);
        short* dst = Apk + (size_t)pos * KTOT + sub * 32;
#pragma unroll
        for (int c = 0; c < 4; ++c) {
            f32x4 f0 = s[2 * c], f1 = s[2 * c + 1];
            bf16x8 o;
            o[0] = f2b(p * f0.x); o[1] = f2b(p * f0.y);
            o[2] = f2b(p * f0.z); o[3] = f2b(p * f0.w);
            o[4] = f2b(p * f1.x); o[5] = f2b(p * f1.y);
            o[6] = f2b(p * f1.z); o[7] = f2b(p * f1.w);
            *(bf16x8*)(dst + c * 8) = o;
        }
    } else {
        __shared__ float Ws[DHD][65];
        int bx = blockIdx.x - 512;
        int h = bx >> 5, m0 = (bx & 31) * 64;
        int tid = threadIdx.x;
        for (int i = tid; i < DHD * 64; i += 256) {
            int d = i >> 6, m = i & 63;
            Ws[d][m] = W[((size_t)h * DHD + d) * DMD + m0 + m];
        }
        __syncthreads();
        for (int i = tid; i < 64 * 16; i += 256) {
            int m = i >> 4, d0 = (i & 15) * 8;
            bf16x8 o;
#pragma unroll
            for (int j = 0; j < 8; ++j) o[j] = f2b(Ws[d0 + j][m]);
            *(bf16x8*)(Wt + ((size_t)h * DMD + m0 + m) * DHD + d0) = o;
        }
    }
}

// GEMM (R15 core, one change: plain stores instead of non-temporal).
// Theory: NT flag bypasses L2 write-combining, forcing partial-line (64B)
// HBM write bursts -> ~2.7 TB/s effective. Each work's stores for a token
// row are contiguous 1KB in aggregate; plain stores let L2 merge them into
// full lines. R18 refuted the segment-pattern theory (coalesced stores via
// LDS gave 0 gain); this isolates the NT flag itself.
__global__ __launch_bounds__(512) void k_gemm(
    const short* __restrict__ Apk, const float* __restrict__ probs,
    const short* __restrict__ Wt, const float* __restrict__ bias,
    const int* __restrict__ perm, const int* __restrict__ cursor,
    float* __restrict__ out) {
    int lin  = blockIdx.x;
    int work = (lin & 7) * 192 + (lin >> 3);
    int tile_id = work >> 3;
    int ncol    = (work & 7) * 256;
    int key = tile_id / 3, s = tile_id - key * 3;
    int nrows = cursor[key * CSTR] - s * 128;
    if (nrows <= 0) return;
    if (nrows > 128) nrows = 128;
    int row0 = key * BCAP + s * 128;
    int h0 = key >> 3, h1 = key & 7;

    __shared__ short As[128 * 64];
    __shared__ short Bs[256 * 64];
    __shared__ int   s_tok[128];
    __shared__ float s_p0[128], s_p1[128];

    int tid = threadIdx.x;
    int lane = tid & 63, wave = tid >> 6;

    if (tid < 128) {
        int t = -1; float p0 = 0.f, p1 = 0.f;
        if (tid < nrows) {
            t = perm[row0 + tid];
            p0 = probs[2 * t];
            p1 = probs[2 * t + 1];
        }
        s_tok[tid] = t; s_p0[tid] = p0; s_p1[tid] = p1;
    }

    f32x4 acc[4][4];
#pragma unroll
    for (int i = 0; i < 4; ++i)
#pragma unroll
        for (int j = 0; j < 4; ++j) acc[i][j] = (f32x4){0.f, 0.f, 0.f, 0.f};

    int wm = (wave >> 2) * 64;
    int wn = (wave & 3) * 64;
    int l15 = lane & 15, lq = lane >> 4;

    int srcr = tid >> 3;
    int cs   = (tid & 7) ^ (srcr & 7);

    for (int ks = 0; ks < 4; ++ks) {
        int h     = (ks < 2) ? h0 : h1;
        int kg0   = ks * 64;
        int dbase = (ks & 1) * 64;
#pragma unroll
        for (int rd = 0; rd < 2; ++rd) {
            int r = rd * 64 + srcr;
            short* ldst = As + (rd * 512 + wave * 64) * 8;
            gll16(Apk + (size_t)(row0 + r) * KTOT + kg0 + cs * 8, ldst);
        }
#pragma unroll
        for (int rd = 0; rd < 4; ++rd) {
            int r = rd * 64 + srcr;
            short* ldst = Bs + (rd * 512 + wave * 64) * 8;
            gll16(Wt + ((size_t)h * DMD + ncol + r) * DHD + dbase + cs * 8, ldst);
        }
        __syncthreads();

#pragma unroll
        for (int ki = 0; ki < 2; ++ki) {
            bf16x8 af[4], bfr[4];
#pragma unroll
            for (int mi = 0; mi < 4; ++mi) {
                int R  = wm + mi * 16 + l15;
                int ch = (ki * 4 + lq) ^ (R & 7);
                af[mi] = *(const bf16x8*)&As[R * 64 + ch * 8];
            }
#pragma unroll
            for (int ni = 0; ni < 4; ++ni) {
                int N  = wn + ni * 16 + l15;
                int ch = (ki * 4 + lq) ^ (N & 7);
                bfr[ni] = *(const bf16x8*)&Bs[N * 64 + ch * 8];
            }
#pragma unroll
            for (int mi = 0; mi < 4; ++mi)
#pragma unroll
                for (int ni = 0; ni < 4; ++ni)
                    acc[mi][ni] = __builtin_amdgcn_mfma_f32_16x16x32_bf16(
                        af[mi], bfr[ni], acc[mi][ni], 0, 0, 0);
        }
        __syncthreads();
    }

    // epilogue: prob-weighted bias, scatter rows to out (PLAIN stores —
    // let L2 write-combine the 64B segments into full lines)
#pragma unroll
    for (int ni = 0; ni < 4; ++ni) {
        int c = ncol + wn + ni * 16 + l15;
        float b0 = bias[h0 * DMD + c];
        float b1 = bias[h1 * DMD + c];
#pragma unroll
        for (int mi = 0; mi < 4; ++mi) {
#pragma unroll
            for (int r = 0; r < 4; ++r) {
                int i = wm + mi * 16 + lq * 4 + r;
                int t = s_tok[i];
                if (t >= 0) {
                    out[(size_t)t * DMD + c] =
                        acc[mi][ni][r] + s_p0[i] * b0 + s_p1[i] * b1;
                }
            }
        }
    }
}

extern "C" void kernel_launch(void* const* d_in, const int* in_sizes, int n_in,
                              void* d_out, int out_size, void* d_ws, size_t ws_size,
                              hipStream_t stream) {
    const float* emb      = (const float*)d_in[0];  // (B,S,A,DH) f32
    const int*   sel_idx  = (const int*)d_in[1];    // (B,S,A) i32
    const float* sel_prob = (const float*)d_in[2];  // (B,S,A) f32
    const float* W        = (const float*)d_in[3];  // (H,DH,DM) f32
    const float* bias     = (const float*)d_in[4];  // (H,DM) f32
    float* out = (float*)d_out;

    char* ws = (char*)d_ws;
    int* cursor = (int*)(ws + 0);
    int* perm   = (int*)(ws + 16384);
    short* Wt   = (short*)(ws + 262144);
    short* Apk  = (short*)(ws + 4456448);

    k_init<<<dim3(4), dim3(1024), 0, stream>>>(cursor);
    k_work<<<dim3(768), dim3(256), 0, stream>>>(
        sel_idx, emb, sel_prob, W, cursor, perm, Apk, Wt);
    k_gemm<<<dim3(1536), dim3(512), 0, stream>>>(
        Apk, sel_prob, Wt, bias, perm, cursor, out);
}